// Round 1
// baseline (19.978 us; speedup 1.0000x reference)
//
#include <hip/hip_runtime.h>
#include <hip/hip_bf16.h>
#include <math.h>

#define S 26
#define D 7
#define DA 11
#define V 29
#define NT 256

__global__ __launch_bounds__(NT) void transformer_fwd(
    const int* __restrict__ x,
    const float* __restrict__ emb_table,
    const float* __restrict__ pos,
    const float* __restrict__ w_k0, const float* __restrict__ b_k0,
    const float* __restrict__ w_q0, const float* __restrict__ b_q0,
    const float* __restrict__ w_v0, const float* __restrict__ b_v0,
    const float* __restrict__ w_f0, const float* __restrict__ b_f0,
    const float* __restrict__ w_k1, const float* __restrict__ b_k1,
    const float* __restrict__ w_q1, const float* __restrict__ b_q1,
    const float* __restrict__ w_v1, const float* __restrict__ b_v1,
    const float* __restrict__ w_f1, const float* __restrict__ b_f1,
    const float* __restrict__ w_out, const float* __restrict__ b_out,
    float* __restrict__ out)
{
    __shared__ float h[S][D];        // current hidden state
    __shared__ float kk[S][DA];
    __shared__ float qq[S][DA];
    __shared__ float vv[S][DA];
    __shared__ float att[S][S];
    __shared__ float res[S][DA];

    const int t = threadIdx.x;

    // ---- embedding: h = emb_table[x] + pos ----
    if (t < S * D) {
        const int s = t / D;
        const int d = t % D;
        h[s][d] = emb_table[x[s] * D + d] + pos[t];
    }
    __syncthreads();

    for (int blk = 0; blk < 2; ++blk) {
        const float* wk = blk ? w_k1 : w_k0;  const float* bk = blk ? b_k1 : b_k0;
        const float* wq = blk ? w_q1 : w_q0;  const float* bq = blk ? b_q1 : b_q0;
        const float* wv = blk ? w_v1 : w_v0;  const float* bv = blk ? b_v1 : b_v0;
        const float* wf = blk ? w_f1 : w_f0;  const float* bf = blk ? b_f1 : b_f0;

        // ---- k, q, v projections: 3 * S * DA = 858 dot products of length D ----
        for (int i = t; i < 3 * S * DA; i += NT) {
            const int which = i / (S * DA);
            const int rem   = i % (S * DA);
            const int r = rem / DA;
            const int c = rem % DA;
            const float* w = (which == 0) ? wk : (which == 1) ? wq : wv;
            const float* b = (which == 0) ? bk : (which == 1) ? bq : bv;
            float acc = b[c];
            #pragma unroll
            for (int d = 0; d < D; ++d) acc += h[r][d] * w[c * D + d];
            float* dst = (which == 0) ? &kk[r][c] : (which == 1) ? &qq[r][c] : &vv[r][c];
            *dst = acc;
        }
        __syncthreads();

        // ---- att = q @ k^T (causal), raw scores; masked entries set to 0 now,
        //      which is exactly what softmax(-inf) produces ----
        for (int i = t; i < S * S; i += NT) {
            const int r = i / S;
            const int c = i % S;
            if (c <= r) {
                float acc = 0.0f;
                #pragma unroll
                for (int d = 0; d < DA; ++d) acc += qq[r][d] * kk[c][d];
                att[r][c] = acc;
            } else {
                att[r][c] = 0.0f;
            }
        }
        __syncthreads();

        // ---- row softmax over the first (r+1) entries; one thread per row ----
        if (t < S) {
            float m = -INFINITY;
            for (int c = 0; c <= t; ++c) m = fmaxf(m, att[t][c]);
            float sum = 0.0f;
            for (int c = 0; c <= t; ++c) {
                const float e = expf(att[t][c] - m);
                att[t][c] = e;
                sum += e;
            }
            const float inv = 1.0f / sum;
            for (int c = 0; c <= t; ++c) att[t][c] *= inv;
        }
        __syncthreads();

        // ---- res = att @ v : S * DA dot products of length (r+1) ----
        for (int i = t; i < S * DA; i += NT) {
            const int r = i / DA;
            const int c = i % DA;
            float acc = 0.0f;
            for (int j = 0; j <= r; ++j) acc += att[r][j] * vv[j][c];
            res[r][c] = acc;
        }
        __syncthreads();

        // ---- h = res @ wf^T + bf : S * D dots of length DA ----
        for (int i = t; i < S * D; i += NT) {
            const int r = i / D;
            const int c = i % D;
            float acc = bf[c];
            #pragma unroll
            for (int j = 0; j < DA; ++j) acc += res[r][j] * wf[c * DA + j];
            h[r][c] = acc;
        }
        __syncthreads();
    }

    // ---- out = h @ w_out^T + b_out : S * V dots of length D ----
    for (int i = t; i < S * V; i += NT) {
        const int r = i / V;
        const int c = i % V;
        float acc = b_out[c];
        #pragma unroll
        for (int d = 0; d < D; ++d) acc += h[r][d] * w_out[c * D + d];
        out[r * V + c] = acc;
    }

    // ---- append att from block 1 (676 floats after the 754 logits) ----
    for (int i = t; i < S * S; i += NT) {
        out[S * V + i] = att[i / S][i % S];
    }
}

extern "C" void kernel_launch(void* const* d_in, const int* in_sizes, int n_in,
                              void* d_out, int out_size, void* d_ws, size_t ws_size,
                              hipStream_t stream) {
    const int*   x         = (const int*)  d_in[0];
    const float* emb_table = (const float*)d_in[1];
    const float* pos       = (const float*)d_in[2];
    const float* w_k0 = (const float*)d_in[3];  const float* b_k0 = (const float*)d_in[4];
    const float* w_q0 = (const float*)d_in[5];  const float* b_q0 = (const float*)d_in[6];
    const float* w_v0 = (const float*)d_in[7];  const float* b_v0 = (const float*)d_in[8];
    const float* w_f0 = (const float*)d_in[9];  const float* b_f0 = (const float*)d_in[10];
    const float* w_k1 = (const float*)d_in[11]; const float* b_k1 = (const float*)d_in[12];
    const float* w_q1 = (const float*)d_in[13]; const float* b_q1 = (const float*)d_in[14];
    const float* w_v1 = (const float*)d_in[15]; const float* b_v1 = (const float*)d_in[16];
    const float* w_f1 = (const float*)d_in[17]; const float* b_f1 = (const float*)d_in[18];
    const float* w_out = (const float*)d_in[19]; const float* b_out = (const float*)d_in[20];
    float* out = (float*)d_out;

    transformer_fwd<<<1, NT, 0, stream>>>(
        x, emb_table, pos,
        w_k0, b_k0, w_q0, b_q0, w_v0, b_v0, w_f0, b_f0,
        w_k1, b_k1, w_q1, b_q1, w_v1, b_v1, w_f1, b_f1,
        w_out, b_out, out);
}

// Round 2
// 18.139 us; speedup vs baseline: 1.1014x; 1.1014x over previous
//
#include <hip/hip_runtime.h>
#include <hip/hip_bf16.h>
#include <math.h>

#define S 26
#define D 7
#define DA 11
#define V 29
#define NT 256

__global__ __launch_bounds__(NT) void transformer_fwd(
    const int* __restrict__ x,
    const float* __restrict__ emb_table,
    const float* __restrict__ pos,
    const float* __restrict__ w_k0, const float* __restrict__ b_k0,
    const float* __restrict__ w_q0, const float* __restrict__ b_q0,
    const float* __restrict__ w_v0, const float* __restrict__ b_v0,
    const float* __restrict__ w_f0, const float* __restrict__ b_f0,
    const float* __restrict__ w_k1, const float* __restrict__ b_k1,
    const float* __restrict__ w_q1, const float* __restrict__ b_q1,
    const float* __restrict__ w_v1, const float* __restrict__ b_v1,
    const float* __restrict__ w_f1, const float* __restrict__ b_f1,
    const float* __restrict__ w_out, const float* __restrict__ b_out,
    float* __restrict__ out)
{
    // ---- LDS arena: all weights + all activations ----
    __shared__ float wk[2][DA * D], bk[2][DA];
    __shared__ float wq[2][DA * D], bq[2][DA];
    __shared__ float wv[2][DA * D], bv[2][DA];
    __shared__ float wf[2][D * DA], bf[2][D];
    __shared__ float wo[V * D], bo[V];
    __shared__ float h[S][D];
    __shared__ float kk[S][DA], qq[S][DA], vv[S][DA];
    __shared__ float att[S][S];
    __shared__ float res[S][DA];

    const int t = threadIdx.x;

    // ================= PREFETCH PHASE =================
    // Issue every global load back-to-back (independent), so only ONE
    // memory-latency exposure sits on the critical path instead of ~14.
    // Every buffer has <= 256 elements -> one element per thread.

    // embedding chain first (2-deep dependent: x -> emb_table gather),
    // so its latency overlaps all the weight loads issued after it.
    const int es = t / D, ed = t % D;
    int   xi   = (t < S * D) ? x[es] : 0;

    float vwk0 = (t < DA * D) ? w_k0[t] : 0.f;
    float vbk0 = (t < DA)     ? b_k0[t] : 0.f;
    float vwq0 = (t < DA * D) ? w_q0[t] : 0.f;
    float vbq0 = (t < DA)     ? b_q0[t] : 0.f;
    float vwv0 = (t < DA * D) ? w_v0[t] : 0.f;
    float vbv0 = (t < DA)     ? b_v0[t] : 0.f;
    float vwf0 = (t < D * DA) ? w_f0[t] : 0.f;
    float vbf0 = (t < D)      ? b_f0[t] : 0.f;
    float vwk1 = (t < DA * D) ? w_k1[t] : 0.f;
    float vbk1 = (t < DA)     ? b_k1[t] : 0.f;
    float vwq1 = (t < DA * D) ? w_q1[t] : 0.f;
    float vbq1 = (t < DA)     ? b_q1[t] : 0.f;
    float vwv1 = (t < DA * D) ? w_v1[t] : 0.f;
    float vbv1 = (t < DA)     ? b_v1[t] : 0.f;
    float vwf1 = (t < D * DA) ? w_f1[t] : 0.f;
    float vbf1 = (t < D)      ? b_f1[t] : 0.f;
    float vwo  = (t < V * D)  ? w_out[t] : 0.f;
    float vbo  = (t < V)      ? b_out[t] : 0.f;
    float vpos = (t < S * D)  ? pos[t]   : 0.f;
    float vemb = (t < S * D)  ? emb_table[xi * D + ed] : 0.f;

    if (t < DA * D) { wk[0][t] = vwk0; wq[0][t] = vwq0; wv[0][t] = vwv0;
                      wk[1][t] = vwk1; wq[1][t] = vwq1; wv[1][t] = vwv1; }
    if (t < D * DA) { wf[0][t] = vwf0; wf[1][t] = vwf1; }
    if (t < DA)     { bk[0][t] = vbk0; bq[0][t] = vbq0; bv[0][t] = vbv0;
                      bk[1][t] = vbk1; bq[1][t] = vbq1; bv[1][t] = vbv1; }
    if (t < D)      { bf[0][t] = vbf0; bf[1][t] = vbf1; }
    if (t < V * D)  wo[t] = vwo;
    if (t < V)      bo[t] = vbo;
    if (t < S * D)  h[es][ed] = vemb + vpos;
    __syncthreads();

    // ================= COMPUTE (LDS-only) =================
    for (int blk = 0; blk < 2; ++blk) {
        // ---- k, q, v projections: 3*S*DA = 858 dots of length D ----
        for (int i = t; i < 3 * S * DA; i += NT) {
            const int which = i / (S * DA);
            const int rem   = i % (S * DA);
            const int r = rem / DA;
            const int c = rem % DA;
            const float* w = (which == 0) ? &wk[blk][0] : (which == 1) ? &wq[blk][0] : &wv[blk][0];
            const float* b = (which == 0) ? &bk[blk][0] : (which == 1) ? &bq[blk][0] : &bv[blk][0];
            float acc = b[c];
            #pragma unroll
            for (int d = 0; d < D; ++d) acc += h[r][d] * w[c * D + d];
            float* dst = (which == 0) ? &kk[r][c] : (which == 1) ? &qq[r][c] : &vv[r][c];
            *dst = acc;
        }
        __syncthreads();

        // ---- att = q @ k^T (causal); masked entries = 0 (== softmax(-inf)) ----
        for (int i = t; i < S * S; i += NT) {
            const int r = i / S;
            const int c = i % S;
            float a = 0.0f;
            if (c <= r) {
                #pragma unroll
                for (int d = 0; d < DA; ++d) a += qq[r][d] * kk[c][d];
            }
            att[r][c] = a;
        }
        __syncthreads();

        // ---- row softmax over first (r+1) entries; one thread per row ----
        if (t < S) {
            float m = -INFINITY;
            for (int c = 0; c <= t; ++c) m = fmaxf(m, att[t][c]);
            float sum = 0.0f;
            for (int c = 0; c <= t; ++c) {
                const float e = __expf(att[t][c] - m);
                att[t][c] = e;
                sum += e;
            }
            const float inv = 1.0f / sum;
            for (int c = 0; c <= t; ++c) att[t][c] *= inv;
        }
        __syncthreads();

        // block-1 att is final after its softmax: stream it to global now so
        // the store overlaps the remaining pv/proj/out compute.
        if (blk == 1) {
            for (int i = t; i < S * S; i += NT)
                out[S * V + i] = att[i / S][i % S];
        }

        // ---- res = att @ v ----
        for (int i = t; i < S * DA; i += NT) {
            const int r = i / DA;
            const int c = i % DA;
            float acc = 0.0f;
            for (int j = 0; j <= r; ++j) acc += att[r][j] * vv[j][c];
            res[r][c] = acc;
        }
        __syncthreads();

        // ---- h = res @ wf^T + bf ----
        for (int i = t; i < S * D; i += NT) {
            const int r = i / D;
            const int c = i % D;
            float acc = bf[blk][c];
            #pragma unroll
            for (int j = 0; j < DA; ++j) acc += res[r][j] * wf[blk][c * DA + j];
            h[r][c] = acc;
        }
        __syncthreads();
    }

    // ---- out = h @ w_out^T + b_out ----
    for (int i = t; i < S * V; i += NT) {
        const int r = i / V;
        const int c = i % V;
        float acc = bo[c];
        #pragma unroll
        for (int d = 0; d < D; ++d) acc += h[r][d] * wo[c * D + d];
        out[r * V + c] = acc;
    }
}

extern "C" void kernel_launch(void* const* d_in, const int* in_sizes, int n_in,
                              void* d_out, int out_size, void* d_ws, size_t ws_size,
                              hipStream_t stream) {
    const int*   x         = (const int*)  d_in[0];
    const float* emb_table = (const float*)d_in[1];
    const float* pos       = (const float*)d_in[2];
    const float* w_k0 = (const float*)d_in[3];  const float* b_k0 = (const float*)d_in[4];
    const float* w_q0 = (const float*)d_in[5];  const float* b_q0 = (const float*)d_in[6];
    const float* w_v0 = (const float*)d_in[7];  const float* b_v0 = (const float*)d_in[8];
    const float* w_f0 = (const float*)d_in[9];  const float* b_f0 = (const float*)d_in[10];
    const float* w_k1 = (const float*)d_in[11]; const float* b_k1 = (const float*)d_in[12];
    const float* w_q1 = (const float*)d_in[13]; const float* b_q1 = (const float*)d_in[14];
    const float* w_v1 = (const float*)d_in[15]; const float* b_v1 = (const float*)d_in[16];
    const float* w_f1 = (const float*)d_in[17]; const float* b_f1 = (const float*)d_in[18];
    const float* w_out = (const float*)d_in[19]; const float* b_out = (const float*)d_in[20];
    float* out = (float*)d_out;

    transformer_fwd<<<1, NT, 0, stream>>>(
        x, emb_table, pos,
        w_k0, b_k0, w_q0, b_q0, w_v0, b_v0, w_f0, b_f0,
        w_k1, b_k1, w_q1, b_q1, w_v1, b_v1, w_f1, b_f1,
        w_out, b_out, out);
}

// Round 3
// 14.377 us; speedup vs baseline: 1.3896x; 1.2616x over previous
//
#include <hip/hip_runtime.h>
#include <hip/hip_bf16.h>
#include <math.h>

#define S 26
#define D 7
#define DA 11
#define V 29
#define NT 256

__global__ __launch_bounds__(NT) void transformer_fwd(
    const int* __restrict__ x,
    const float* __restrict__ emb_table,
    const float* __restrict__ pos,
    const float* __restrict__ w_k0, const float* __restrict__ b_k0,
    const float* __restrict__ w_q0, const float* __restrict__ b_q0,
    const float* __restrict__ w_v0, const float* __restrict__ b_v0,
    const float* __restrict__ w_f0, const float* __restrict__ b_f0,
    const float* __restrict__ w_k1, const float* __restrict__ b_k1,
    const float* __restrict__ w_q1, const float* __restrict__ b_q1,
    const float* __restrict__ w_v1, const float* __restrict__ b_v1,
    const float* __restrict__ w_f1, const float* __restrict__ b_f1,
    const float* __restrict__ w_out, const float* __restrict__ b_out,
    float* __restrict__ out)
{
    // ---- LDS arena: all weights + all activations ----
    __shared__ float wk[2][DA * D], bk[2][DA];
    __shared__ float wq[2][DA * D], bq[2][DA];
    __shared__ float wv[2][DA * D], bv[2][DA];
    __shared__ float wf[2][D * DA], bf[2][D];
    __shared__ float wo[V * D], bo[V];
    __shared__ float h[S][D];
    __shared__ float kk[S][DA], qq[S][DA], vv[S][DA];
    __shared__ float att[S][S];
    __shared__ float res[S][DA];

    const int t = threadIdx.x;

    // ================= PREFETCH PHASE =================
    // One batched latency exposure: every global load issued back-to-back.
    const int es = t / D, ed = t % D;
    int   xi   = (t < S * D) ? x[es] : 0;

    float vwk0 = (t < DA * D) ? w_k0[t] : 0.f;
    float vbk0 = (t < DA)     ? b_k0[t] : 0.f;
    float vwq0 = (t < DA * D) ? w_q0[t] : 0.f;
    float vbq0 = (t < DA)     ? b_q0[t] : 0.f;
    float vwv0 = (t < DA * D) ? w_v0[t] : 0.f;
    float vbv0 = (t < DA)     ? b_v0[t] : 0.f;
    float vwf0 = (t < D * DA) ? w_f0[t] : 0.f;
    float vbf0 = (t < D)      ? b_f0[t] : 0.f;
    float vwk1 = (t < DA * D) ? w_k1[t] : 0.f;
    float vbk1 = (t < DA)     ? b_k1[t] : 0.f;
    float vwq1 = (t < DA * D) ? w_q1[t] : 0.f;
    float vbq1 = (t < DA)     ? b_q1[t] : 0.f;
    float vwv1 = (t < DA * D) ? w_v1[t] : 0.f;
    float vbv1 = (t < DA)     ? b_v1[t] : 0.f;
    float vwf1 = (t < D * DA) ? w_f1[t] : 0.f;
    float vbf1 = (t < D)      ? b_f1[t] : 0.f;
    float vwo  = (t < V * D)  ? w_out[t] : 0.f;
    float vbo  = (t < V)      ? b_out[t] : 0.f;
    float vpos = (t < S * D)  ? pos[t]   : 0.f;
    float vemb = (t < S * D)  ? emb_table[xi * D + ed] : 0.f;

    if (t < DA * D) { wk[0][t] = vwk0; wq[0][t] = vwq0; wv[0][t] = vwv0;
                      wk[1][t] = vwk1; wq[1][t] = vwq1; wv[1][t] = vwv1; }
    if (t < D * DA) { wf[0][t] = vwf0; wf[1][t] = vwf1; }
    if (t < DA)     { bk[0][t] = vbk0; bq[0][t] = vbq0; bv[0][t] = vbv0;
                      bk[1][t] = vbk1; bq[1][t] = vbq1; bv[1][t] = vbv1; }
    if (t < D)      { bf[0][t] = vbf0; bf[1][t] = vbf1; }
    if (t < V * D)  wo[t] = vwo;
    if (t < V)      bo[t] = vbo;
    if (t < S * D)  h[es][ed] = vemb + vpos;
    __syncthreads();

    // ================= COMPUTE (LDS-only, all inner loops static) ==========
    for (int blk = 0; blk < 2; ++blk) {
        // ---- k, q, v projections ----
        for (int i = t; i < 3 * S * DA; i += NT) {
            const int which = i / (S * DA);
            const int rem   = i % (S * DA);
            const int r = rem / DA;
            const int c = rem % DA;
            const float* w = (which == 0) ? &wk[blk][0] : (which == 1) ? &wq[blk][0] : &wv[blk][0];
            const float* b = (which == 0) ? &bk[blk][0] : (which == 1) ? &bq[blk][0] : &bv[blk][0];
            float acc = b[c];
            #pragma unroll
            for (int d = 0; d < D; ++d) acc += h[r][d] * w[c * D + d];
            float* dst = (which == 0) ? &kk[r][c] : (which == 1) ? &qq[r][c] : &vv[r][c];
            *dst = acc;
        }
        __syncthreads();

        // ---- att = q @ k^T (causal); masked entries = 0 (== softmax(-inf)) ----
        for (int i = t; i < S * S; i += NT) {
            const int r = i / S;
            const int c = i % S;
            float a = 0.0f;
            if (c <= r) {
                #pragma unroll
                for (int d = 0; d < DA; ++d) a += qq[r][d] * kk[c][d];
            }
            att[r][c] = a;
        }
        __syncthreads();

        // ---- row softmax: lane-per-row, whole row in REGISTERS, static loops.
        //      26 independent ds_reads batch under one waitcnt instead of a
        //      ~120-cycle latency exposure per iteration.
        if (t < S) {
            float a[S], e[S];
            #pragma unroll
            for (int c = 0; c < S; ++c) a[c] = att[t][c];
            float m = a[0];                       // c=0 always unmasked
            #pragma unroll
            for (int c = 1; c < S; ++c) m = fmaxf(m, (c <= t) ? a[c] : -INFINITY);
            float sum = 0.0f;
            #pragma unroll
            for (int c = 0; c < S; ++c) {
                e[c] = (c <= t) ? __expf(a[c] - m) : 0.0f;
                sum += e[c];
            }
            const float inv = 1.0f / sum;
            #pragma unroll
            for (int c = 0; c < S; ++c) att[t][c] = e[c] * inv;
        }
        __syncthreads();

        // block-1 att is final after softmax: stream to global now, overlapping
        // the remaining pv/proj/out compute.
        if (blk == 1) {
            for (int i = t; i < S * S; i += NT)
                out[S * V + i] = att[i / S][i % S];
        }

        // ---- res = att @ v : full static 26-loop (masked att entries are 0) ----
        for (int i = t; i < S * DA; i += NT) {
            const int r = i / DA;
            const int c = i % DA;
            float acc = 0.0f;
            #pragma unroll
            for (int j = 0; j < S; ++j) acc += att[r][j] * vv[j][c];
            res[r][c] = acc;
        }
        __syncthreads();

        // ---- h = res @ wf^T + bf ----
        for (int i = t; i < S * D; i += NT) {
            const int r = i / D;
            const int c = i % D;
            float acc = bf[blk][c];
            #pragma unroll
            for (int j = 0; j < DA; ++j) acc += res[r][j] * wf[blk][c * DA + j];
            h[r][c] = acc;
        }
        __syncthreads();
    }

    // ---- out = h @ w_out^T + b_out ----
    for (int i = t; i < S * V; i += NT) {
        const int r = i / V;
        const int c = i % V;
        float acc = bo[c];
        #pragma unroll
        for (int d = 0; d < D; ++d) acc += h[r][d] * wo[c * D + d];
        out[r * V + c] = acc;
    }
}

extern "C" void kernel_launch(void* const* d_in, const int* in_sizes, int n_in,
                              void* d_out, int out_size, void* d_ws, size_t ws_size,
                              hipStream_t stream) {
    const int*   x         = (const int*)  d_in[0];
    const float* emb_table = (const float*)d_in[1];
    const float* pos       = (const float*)d_in[2];
    const float* w_k0 = (const float*)d_in[3];  const float* b_k0 = (const float*)d_in[4];
    const float* w_q0 = (const float*)d_in[5];  const float* b_q0 = (const float*)d_in[6];
    const float* w_v0 = (const float*)d_in[7];  const float* b_v0 = (const float*)d_in[8];
    const float* w_f0 = (const float*)d_in[9];  const float* b_f0 = (const float*)d_in[10];
    const float* w_k1 = (const float*)d_in[11]; const float* b_k1 = (const float*)d_in[12];
    const float* w_q1 = (const float*)d_in[13]; const float* b_q1 = (const float*)d_in[14];
    const float* w_v1 = (const float*)d_in[15]; const float* b_v1 = (const float*)d_in[16];
    const float* w_f1 = (const float*)d_in[17]; const float* b_f1 = (const float*)d_in[18];
    const float* w_out = (const float*)d_in[19]; const float* b_out = (const float*)d_in[20];
    float* out = (float*)d_out;

    transformer_fwd<<<1, NT, 0, stream>>>(
        x, emb_table, pos,
        w_k0, b_k0, w_q0, b_q0, w_v0, b_v0, w_f0, b_f0,
        w_k1, b_k1, w_q1, b_q1, w_v1, b_v1, w_f1, b_f1,
        w_out, b_out, out);
}

// Round 4
// 12.217 us; speedup vs baseline: 1.6353x; 1.1768x over previous
//
#include <hip/hip_runtime.h>
#include <hip/hip_bf16.h>
#include <math.h>

#define S 26
#define D 7
#define DA 11
#define V 29
#define NT 256

__device__ __forceinline__ float dot8(float4 a0, float4 a1, float4 b0, float4 b1) {
    return a0.x*b0.x + a0.y*b0.y + a0.z*b0.z + a0.w*b0.w
         + a1.x*b1.x + a1.y*b1.y + a1.z*b1.z + a1.w*b1.w;
}
__device__ __forceinline__ float dot12(float4 a0, float4 a1, float4 a2,
                                       float4 b0, float4 b1, float4 b2) {
    return a0.x*b0.x + a0.y*b0.y + a0.z*b0.z + a0.w*b0.w
         + a1.x*b1.x + a1.y*b1.y + a1.z*b1.z + a1.w*b1.w
         + a2.x*b2.x + a2.y*b2.y + a2.z*b2.z + a2.w*b2.w;
}

__global__ __launch_bounds__(NT) void transformer_fwd(
    const int* __restrict__ x,
    const float* __restrict__ emb_table,
    const float* __restrict__ pos,
    const float* __restrict__ w_k0, const float* __restrict__ b_k0,
    const float* __restrict__ w_q0, const float* __restrict__ b_q0,
    const float* __restrict__ w_v0, const float* __restrict__ b_v0,
    const float* __restrict__ w_f0, const float* __restrict__ b_f0,
    const float* __restrict__ w_k1, const float* __restrict__ b_k1,
    const float* __restrict__ w_q1, const float* __restrict__ b_q1,
    const float* __restrict__ w_v1, const float* __restrict__ b_v1,
    const float* __restrict__ w_f1, const float* __restrict__ b_f1,
    const float* __restrict__ w_out, const float* __restrict__ b_out,
    float* __restrict__ out)
{
    // ---- LDS arena, all float4-typed, padded with ZEROS so every dot runs
    //      full-width with no masking. Pads: weight rows/cols zero =>
    //      padded activation entries compute to exactly 0.
    __shared__ float4 wkv[2][12][2], wqv[2][12][2], wvv[2][12][2]; // [DA->12][D->8]
    __shared__ float4 wfv[2][8][3];                                // [D->8][DA->12]
    __shared__ float4 wov[32][2];                                  // [V->32][D->8]
    __shared__ float4 bkv[2][3], bqv[2][3], bvv[2][3], bfv[2][2];  // 12 / 8
    __shared__ float  bos[32];
    __shared__ float4 hv[S][2];          // h[26][8], col 7 == 0
    __shared__ float4 kkv[28][3];        // k[28][12], rows 26,27 & col 11 == 0
    __shared__ float4 qqv[S][3], vvv[S][3];
    __shared__ float4 attv[S][7];        // att[26][28], cols 26,27 == 0
    __shared__ float4 resv[S][3];        // res[26][12], col 11 == 0

    const int t = threadIdx.x;

    // ================= PREFETCH (one batched latency exposure) =============
    {
        // embedding chain first (2-deep: x -> emb gather)
        const int es = t >> 3, ed = t & 7;                 // h padded stride 8
        float hval = 0.f;
        if (t < S * 8) {
            if (ed < D) {
                const int xi = x[es];
                hval = emb_table[xi * D + ed] + pos[es * D + ed];
            }
            ((float*)hv)[t] = hval;
        }
        if (t < 96) {  // wk/wq/wv [12][8]
            const int r = t >> 3, c = t & 7;
            const bool v = (r < DA) && (c < D);
            const int idx = r * D + c;
            ((float*)wkv[0])[t] = v ? w_k0[idx] : 0.f;
            ((float*)wkv[1])[t] = v ? w_k1[idx] : 0.f;
            ((float*)wqv[0])[t] = v ? w_q0[idx] : 0.f;
            ((float*)wqv[1])[t] = v ? w_q1[idx] : 0.f;
            ((float*)wvv[0])[t] = v ? w_v0[idx] : 0.f;
            ((float*)wvv[1])[t] = v ? w_v1[idx] : 0.f;
            // wf [8][12]
            const int rf = t / 12, cf = t % 12;
            const bool vf = (rf < D) && (cf < DA);
            const int idxf = rf * DA + cf;
            ((float*)wfv[0])[t] = vf ? w_f0[idxf] : 0.f;
            ((float*)wfv[1])[t] = vf ? w_f1[idxf] : 0.f;
        }
        {   // wo [32][8] : 256 entries, every thread
            const int r = t >> 3, c = t & 7;
            const bool v = (r < V) && (c < D);
            ((float*)wov)[t] = v ? w_out[r * D + c] : 0.f;
        }
        if (t < 12) {
            ((float*)bkv[0])[t] = (t < DA) ? b_k0[t] : 0.f;
            ((float*)bkv[1])[t] = (t < DA) ? b_k1[t] : 0.f;
            ((float*)bqv[0])[t] = (t < DA) ? b_q0[t] : 0.f;
            ((float*)bqv[1])[t] = (t < DA) ? b_q1[t] : 0.f;
            ((float*)bvv[0])[t] = (t < DA) ? b_v0[t] : 0.f;
            ((float*)bvv[1])[t] = (t < DA) ? b_v1[t] : 0.f;
        }
        if (t < 8) {
            ((float*)bfv[0])[t] = (t < D) ? b_f0[t] : 0.f;
            ((float*)bfv[1])[t] = (t < D) ? b_f1[t] : 0.f;
        }
        if (t < 32) bos[t] = (t < V) ? b_out[t] : 0.f;
        if (t < 24) ((float*)kkv)[26 * 12 + t] = 0.f;   // kk pad rows 26,27
    }
    __syncthreads();

    // ================= COMPUTE: all LDS traffic is float4 ==================
    for (int blk = 0; blk < 2; ++blk) {
        // ---- kqv: 234 items, each computes a float4 of one projection row --
        if (t < 234) {
            const int type = t / 78, rem = t % 78;
            const int r = rem / 3, c4 = rem % 3;
            const float4* W = (type == 0) ? &wkv[blk][0][0]
                             : (type == 1) ? &wqv[blk][0][0] : &wvv[blk][0][0];
            const float4  bb = ((type == 0) ? bkv[blk] : (type == 1) ? bqv[blk] : bvv[blk])[c4];
            const float4 h0 = hv[r][0], h1 = hv[r][1];
            const int c0 = c4 * 4;
            float4 o;
            o.x = dot8(h0, h1, W[(c0 + 0) * 2], W[(c0 + 0) * 2 + 1]) + bb.x;
            o.y = dot8(h0, h1, W[(c0 + 1) * 2], W[(c0 + 1) * 2 + 1]) + bb.y;
            o.z = dot8(h0, h1, W[(c0 + 2) * 2], W[(c0 + 2) * 2 + 1]) + bb.z;
            o.w = dot8(h0, h1, W[(c0 + 3) * 2], W[(c0 + 3) * 2 + 1]) + bb.w;
            float4* DST = (type == 0) ? &kkv[r][c4] : (type == 1) ? &qqv[r][c4] : &vvv[r][c4];
            *DST = o;
        }
        __syncthreads();

        // ---- att = q @ k^T (causal), float4 output groups: 182 items -------
        if (t < 182) {
            const int r = t / 7, c4 = t % 7;
            const float4 q0 = qqv[r][0], q1 = qqv[r][1], q2 = qqv[r][2];
            float vo[4];
            #pragma unroll
            for (int cc = 0; cc < 4; ++cc) {
                const int c = c4 * 4 + cc;
                const float d = dot12(q0, q1, q2, kkv[c][0], kkv[c][1], kkv[c][2]);
                vo[cc] = (c <= r) ? d : 0.f;
            }
            attv[r][c4] = make_float4(vo[0], vo[1], vo[2], vo[3]);
        }
        __syncthreads();

        // ---- softmax: lane-per-row, row in registers, static loops ---------
        if (t < S) {
            float a[28];
            #pragma unroll
            for (int j = 0; j < 7; ++j) {
                const float4 aa = attv[t][j];
                a[4*j] = aa.x; a[4*j+1] = aa.y; a[4*j+2] = aa.z; a[4*j+3] = aa.w;
            }
            float m = a[0];
            #pragma unroll
            for (int c = 1; c < S; ++c) m = fmaxf(m, (c <= t) ? a[c] : -INFINITY);
            float e[S];
            float sum = 0.f;
            #pragma unroll
            for (int c = 0; c < S; ++c) {
                e[c] = (c <= t) ? __expf(a[c] - m) : 0.f;
                sum += e[c];
            }
            const float inv = 1.f / sum;
            #pragma unroll
            for (int j = 0; j < 7; ++j) {
                float4 o;
                o.x = e[4*j] * inv;
                o.y = (4*j+1 < S) ? e[4*j+1] * inv : 0.f;
                o.z = (4*j+2 < S) ? e[4*j+2] * inv : 0.f;
                o.w = (4*j+3 < S) ? e[4*j+3] * inv : 0.f;
                attv[t][j] = o;
            }
        }
        __syncthreads();

        // block-1 att final: stream to global, overlaps remaining compute
        if (blk == 1) {
            const float* atts = (const float*)attv;
            for (int i = t; i < S * S; i += NT) {
                const int r = i / S, c = i % S;
                out[S * V + i] = atts[r * 28 + c];
            }
        }

        // ---- res = att @ v : 78 items, float4 accumulate -------------------
        if (t < 78) {
            const int r = t / 3, c4 = t % 3;
            float a[28];
            #pragma unroll
            for (int j = 0; j < 7; ++j) {
                const float4 aa = attv[r][j];
                a[4*j] = aa.x; a[4*j+1] = aa.y; a[4*j+2] = aa.z; a[4*j+3] = aa.w;
            }
            float4 acc = make_float4(0.f, 0.f, 0.f, 0.f);
            #pragma unroll
            for (int j = 0; j < S; ++j) {
                const float aj = a[j];
                const float4 vj = vvv[j][c4];
                acc.x += aj * vj.x; acc.y += aj * vj.y;
                acc.z += aj * vj.z; acc.w += aj * vj.w;
            }
            resv[r][c4] = acc;
        }
        __syncthreads();

        // ---- h = res @ wf^T + bf : 52 items ------------------------------
        if (t < 52) {
            const int r = t >> 1, c4 = t & 1;
            const float4 r0 = resv[r][0], r1 = resv[r][1], r2 = resv[r][2];
            const float4 bb = bfv[blk][c4];
            const int c0 = c4 * 4;
            float4 o;
            o.x = dot12(r0, r1, r2, wfv[blk][c0+0][0], wfv[blk][c0+0][1], wfv[blk][c0+0][2]) + bb.x;
            o.y = dot12(r0, r1, r2, wfv[blk][c0+1][0], wfv[blk][c0+1][1], wfv[blk][c0+1][2]) + bb.y;
            o.z = dot12(r0, r1, r2, wfv[blk][c0+2][0], wfv[blk][c0+2][1], wfv[blk][c0+2][2]) + bb.z;
            o.w = dot12(r0, r1, r2, wfv[blk][c0+3][0], wfv[blk][c0+3][1], wfv[blk][c0+3][2]) + bb.w;
            hv[r][c4] = o;
        }
        __syncthreads();
    }

    // ---- out = h @ w_out^T + b_out : 208 items, 4 outputs each ------------
    if (t < 208) {
        const int r = t >> 3, c4 = t & 7;
        const float4 h0 = hv[r][0], h1 = hv[r][1];
        #pragma unroll
        for (int cc = 0; cc < 4; ++cc) {
            const int c = c4 * 4 + cc;
            const float d = dot8(h0, h1, wov[c][0], wov[c][1]) + bos[c];
            if (c < V) out[r * V + c] = d;
        }
    }
}

extern "C" void kernel_launch(void* const* d_in, const int* in_sizes, int n_in,
                              void* d_out, int out_size, void* d_ws, size_t ws_size,
                              hipStream_t stream) {
    const int*   x         = (const int*)  d_in[0];
    const float* emb_table = (const float*)d_in[1];
    const float* pos       = (const float*)d_in[2];
    const float* w_k0 = (const float*)d_in[3];  const float* b_k0 = (const float*)d_in[4];
    const float* w_q0 = (const float*)d_in[5];  const float* b_q0 = (const float*)d_in[6];
    const float* w_v0 = (const float*)d_in[7];  const float* b_v0 = (const float*)d_in[8];
    const float* w_f0 = (const float*)d_in[9];  const float* b_f0 = (const float*)d_in[10];
    const float* w_k1 = (const float*)d_in[11]; const float* b_k1 = (const float*)d_in[12];
    const float* w_q1 = (const float*)d_in[13]; const float* b_q1 = (const float*)d_in[14];
    const float* w_v1 = (const float*)d_in[15]; const float* b_v1 = (const float*)d_in[16];
    const float* w_f1 = (const float*)d_in[17]; const float* b_f1 = (const float*)d_in[18];
    const float* w_out = (const float*)d_in[19]; const float* b_out = (const float*)d_in[20];
    float* out = (float*)d_out;

    transformer_fwd<<<1, NT, 0, stream>>>(
        x, emb_table, pos,
        w_k0, b_k0, w_q0, b_q0, w_v0, b_v0, w_f0, b_f0,
        w_k1, b_k1, w_q1, b_q1, w_v1, b_v1, w_f1, b_f1,
        w_out, b_out, out);
}